// Round 11
// baseline (3213.616 us; speedup 1.0000x reference)
//
#include <hip/hip_runtime.h>
#include <math.h>

// Problem constants
#define BB   32
#define NN   197
#define CC   768
#define HH   12
#define DD   64
#define KWW  197
#define HIDD 3072
#define NL   12
#define RR   (BB*NN)      // 6304 rows
#define BHH  (BB*HH)      // 384 batch*head
#define NP   224          // n/kw padded to multiple of 32 (for MFMA K dim)
#define SLS  232          // S1s LDS row stride (bank spread)

typedef __attribute__((ext_vector_type(8))) short short8;
typedef __attribute__((ext_vector_type(4))) float floatx4;
typedef __attribute__((ext_vector_type(4))) unsigned short us4;

__device__ __forceinline__ unsigned short f2bf(float f) {
    unsigned int u = __float_as_uint(f);
    u += 0x7fff + ((u >> 16) & 1);          // round-to-nearest-even
    return (unsigned short)(u >> 16);
}

// ---------------------------------------------------------------------------
// LayerNorm over C=768 -> bf16 output. One block (192 thr) per row, float4.
__global__ void ln768_kernel(const float* __restrict__ in, const float* __restrict__ g,
                             const float* __restrict__ be, unsigned short* __restrict__ out) {
    int row = blockIdx.x;
    int t = threadIdx.x;                 // 0..191
    float4 v = ((const float4*)(in + (size_t)row * CC))[t];
    float s = v.x+v.y+v.z+v.w;
    float q = v.x*v.x+v.y*v.y+v.z*v.z+v.w*v.w;
    for (int off = 1; off < 64; off <<= 1) {
        s += __shfl_xor(s, off, 64);
        q += __shfl_xor(q, off, 64);
    }
    __shared__ float sh[6];
    int wv = t >> 6, ln = t & 63;
    if (ln == 0) { sh[wv] = s; sh[3+wv] = q; }
    __syncthreads();
    s = sh[0]+sh[1]+sh[2];
    q = sh[3]+sh[4]+sh[5];
    float mu  = s * (1.0f/CC);
    float var = q * (1.0f/CC) - mu*mu;
    float rs  = rsqrtf(var + 1e-5f);
    float4 gv = ((const float4*)g)[t];
    float4 bv = ((const float4*)be)[t];
    us4 o = { f2bf((v.x-mu)*rs*gv.x + bv.x), f2bf((v.y-mu)*rs*gv.y + bv.y),
              f2bf((v.z-mu)*rs*gv.z + bv.z), f2bf((v.w-mu)*rs*gv.w + bv.w) };
    *(us4*)(out + (size_t)row*CC + t*4) = o;
}

// ---------------------------------------------------------------------------
// Fused init: x1 = x2 = x, and LN(x) -> lnb (layer-0 f-LN). 192 thr, float4.
__global__ void init_ln(const float* __restrict__ x, float* __restrict__ x1,
                        float* __restrict__ x2,
                        const float* __restrict__ g, const float* __restrict__ be,
                        unsigned short* __restrict__ out) {
    int row = blockIdx.x;
    int t = threadIdx.x;
    float4 v = ((const float4*)(x + (size_t)row * CC))[t];
    ((float4*)(x1 + (size_t)row * CC))[t] = v;
    ((float4*)(x2 + (size_t)row * CC))[t] = v;
    float s = v.x+v.y+v.z+v.w;
    float q = v.x*v.x+v.y*v.y+v.z*v.z+v.w*v.w;
    for (int off = 1; off < 64; off <<= 1) {
        s += __shfl_xor(s, off, 64);
        q += __shfl_xor(q, off, 64);
    }
    __shared__ float sh[6];
    int wv = t >> 6, ln = t & 63;
    if (ln == 0) { sh[wv] = s; sh[3+wv] = q; }
    __syncthreads();
    s = sh[0]+sh[1]+sh[2];
    q = sh[3]+sh[4]+sh[5];
    float mu  = s * (1.0f/CC);
    float var = q * (1.0f/CC) - mu*mu;
    float rs  = rsqrtf(var + 1e-5f);
    float4 gv = ((const float4*)g)[t];
    float4 bv = ((const float4*)be)[t];
    us4 o = { f2bf((v.x-mu)*rs*gv.x + bv.x), f2bf((v.y-mu)*rs*gv.y + bv.y),
              f2bf((v.z-mu)*rs*gv.z + bv.z), f2bf((v.w-mu)*rs*gv.w + bv.w) };
    *(us4*)(out + (size_t)row*CC + t*4) = o;
}

// ---------------------------------------------------------------------------
// Fused: x2 += part0 + part1 + b2; then
//   mode 1: LN(x2_new) -> out (next layer f-LN)
//   mode 2: final output: outf = 0.5*(x1 + x2_new)
// 192 threads per row, float4 path.
__global__ void reduce_ln(float* __restrict__ x2, const float* __restrict__ part,
                          const float* __restrict__ b2,
                          const float* __restrict__ g, const float* __restrict__ be,
                          unsigned short* __restrict__ out,
                          const float* __restrict__ x1f, float* __restrict__ outf,
                          int mode) {
    int row = blockIdx.x;
    int t = threadIdx.x;
    float4 v  = ((float4*)(x2 + (size_t)row * CC))[t];
    float4 a0 = ((const float4*)(part + (size_t)row * CC))[t];
    float4 a1 = ((const float4*)(part + (size_t)RR*CC + (size_t)row * CC))[t];
    float4 bb = ((const float4*)b2)[t];
    v.x += a0.x + a1.x + bb.x;
    v.y += a0.y + a1.y + bb.y;
    v.z += a0.z + a1.z + bb.z;
    v.w += a0.w + a1.w + bb.w;
    ((float4*)(x2 + (size_t)row * CC))[t] = v;
    if (mode == 2) {
        float4 xo = ((const float4*)(x1f + (size_t)row * CC))[t];
        float4 o;
        o.x = 0.5f*(xo.x + v.x); o.y = 0.5f*(xo.y + v.y);
        o.z = 0.5f*(xo.z + v.z); o.w = 0.5f*(xo.w + v.w);
        ((float4*)(outf + (size_t)row * CC))[t] = o;
        return;
    }
    float s = v.x+v.y+v.z+v.w;
    float q = v.x*v.x+v.y*v.y+v.z*v.z+v.w*v.w;
    for (int off = 1; off < 64; off <<= 1) {
        s += __shfl_xor(s, off, 64);
        q += __shfl_xor(q, off, 64);
    }
    __shared__ float sh[6];
    int wv = t >> 6, ln = t & 63;
    if (ln == 0) { sh[wv] = s; sh[3+wv] = q; }
    __syncthreads();
    s = sh[0]+sh[1]+sh[2];
    q = sh[3]+sh[4]+sh[5];
    float mu  = s * (1.0f/CC);
    float var = q * (1.0f/CC) - mu*mu;
    float rs  = rsqrtf(var + 1e-5f);
    float4 gv = ((const float4*)g)[t];
    float4 bv = ((const float4*)be)[t];
    us4 o = { f2bf((v.x-mu)*rs*gv.x + bv.x), f2bf((v.y-mu)*rs*gv.y + bv.y),
              f2bf((v.z-mu)*rs*gv.z + bv.z), f2bf((v.w-mu)*rs*gv.w + bv.w) };
    *(us4*)(out + (size_t)row*CC + t*4) = o;
}

// ---------------------------------------------------------------------------
// Transpose + cast fp32 [K][Nd] -> bf16 [Nd][Kpad], zero-filling k in [K,Kpad).
__global__ void transpose_cast(const float* __restrict__ in, unsigned short* __restrict__ out,
                               int K, int Nd, int Kpad) {
    __shared__ float tile[32][33];
    int n0 = blockIdx.x*32, k0 = blockIdx.y*32;
    int tx = threadIdx.x & 31, ty = threadIdx.x >> 5;   // 32 x 8
    #pragma unroll
    for (int i = 0; i < 4; i++) {
        int k = k0 + ty + i*8;
        tile[ty + i*8][tx] = (k < K && n0+tx < Nd) ? in[(size_t)k*Nd + n0 + tx] : 0.f;
    }
    __syncthreads();
    #pragma unroll
    for (int i = 0; i < 4; i++) {
        int n = n0 + ty + i*8;
        if (n < Nd && k0 + tx < Kpad) out[(size_t)n*Kpad + k0 + tx] = f2bf(tile[tx][ty + i*8]);
    }
}

// ---------------------------------------------------------------------------
// bf16 MFMA GEMM: C = A(bf16,[M][K]) @ Bt(bf16,[Nd][K])^T.
// 128x128 tile, BK=64, 256 thr (4 waves, 2x2), single-buffer 2-barrier loop.
// Proven plateau for this problem's shapes: 0 bank conflicts, ~43 MB fetch
// (QKV), ~60 us. Prefetch restructurings all regressed (r1/r2/r4/r9) - closed.
//  - LDS XOR swizzle: phys 16B slot = logical ^ (row&7); inverse permutation
//    applied to per-lane GLOBAL source column; reads XOR back.
//  - Bijective XCD-aware blockIdx remap (m204) for per-XCD L2 locality.
// EPI: 2 = +bias fast-GELU store bf16; 4 = QKV scatter; 5 = fp32 split-K partial.
template<int EPI, int KS>
__global__ __launch_bounds__(256) void gemm128(
    const unsigned short* __restrict__ A, const unsigned short* __restrict__ Bt,
    const float* __restrict__ bias, float* __restrict__ Cf, unsigned short* __restrict__ Cb,
    int M, int Nd, int K)
{
    __shared__ unsigned short As[128*64];   // 16 KiB, [row][64 cols], 128B rows
    __shared__ unsigned short Bs[128*64];   // 16 KiB
    int tid  = threadIdx.x;
    int wv   = tid >> 6, lane = tid & 63;
    int wm   = wv >> 1, wn = wv & 1;
    int quad = lane >> 4, mrow = lane & 15;
    int rl   = lane >> 3, ps = lane & 7;    // staging: 8 lanes/row, 16B each

    // XCD-aware bijective chunked remap (m204)
    int gx   = gridDim.x;
    int nwg  = gx * gridDim.y;
    int orig = blockIdx.y * gx + blockIdx.x;
    int qq = nwg >> 3, rr = nwg & 7;
    int xcd = orig & 7, idx = orig >> 3;
    int wg  = (xcd < rr ? xcd*(qq+1) : rr*(qq+1) + (xcd-rr)*qq) + idx;
    int bm  = (wg / gx) * 128;
    int bn  = (wg % gx) * 128;

    const int Kc    = K / KS;
    const int kbase = (KS > 1) ? blockIdx.z * Kc : 0;

    floatx4 acc[4][4];
    #pragma unroll
    for (int i = 0; i < 4; i++)
        #pragma unroll
        for (int j = 0; j < 4; j++) acc[i][j] = (floatx4){0.f,0.f,0.f,0.f};

    for (int k0 = kbase; k0 < kbase + Kc; k0 += 64) {
        // stage A rows [wv*32, wv*32+32): 4 issues x 8 rows, inverse-swz source
        #pragma unroll
        for (int i = 0; i < 4; i++) {
            int r_ = wv*32 + i*8 + rl;
            int sl = ps ^ (r_ & 7);
            int gr = bm + r_; if (gr > M-1) gr = M-1;
            __builtin_amdgcn_global_load_lds(
                (const __attribute__((address_space(1))) void*)(A + (size_t)gr*K + k0 + sl*8),
                (__attribute__((address_space(3))) void*)(As + (wv*32 + i*8)*64),
                16, 0, 0);
        }
        #pragma unroll
        for (int i = 0; i < 4; i++) {
            int r_ = wv*32 + i*8 + rl;
            int sl = ps ^ (r_ & 7);
            int gr = bn + r_;
            __builtin_amdgcn_global_load_lds(
                (const __attribute__((address_space(1))) void*)(Bt + (size_t)gr*K + k0 + sl*8),
                (__attribute__((address_space(3))) void*)(Bs + (wv*32 + i*8)*64),
                16, 0, 0);
        }
        __syncthreads();
        #pragma unroll
        for (int kk = 0; kk < 2; kk++) {
            short8 af[4], bf[4];
            #pragma unroll
            for (int mi = 0; mi < 4; mi++) {
                int lr = wm*64 + mi*16 + mrow;
                af[mi] = *(const short8*)&As[lr*64 + (((kk<<2)|quad) ^ (lr & 7))*8];
            }
            #pragma unroll
            for (int ni = 0; ni < 4; ni++) {
                int lr = wn*64 + ni*16 + mrow;
                bf[ni] = *(const short8*)&Bs[lr*64 + (((kk<<2)|quad) ^ (lr & 7))*8];
            }
            #pragma unroll
            for (int mi = 0; mi < 4; mi++)
                #pragma unroll
                for (int ni = 0; ni < 4; ni++)
                    acc[mi][ni] = __builtin_amdgcn_mfma_f32_16x16x32_bf16(
                        af[mi], bf[ni], acc[mi][ni], 0, 0, 0);
        }
        __syncthreads();
    }

    // ---- epilogue
    float* Cfz = (EPI == 5) ? (Cf + (size_t)blockIdx.z * M * Nd) : Cf;
    #pragma unroll
    for (int mi = 0; mi < 4; mi++) {
        int row0 = bm + wm*64 + mi*16 + quad*4;
        // EPI==4: precompute b,n per r (hoists row/NN out of the ni loop)
        int bA[4], nA[4];
        if (EPI == 4) {
            int b0 = row0 / NN, n0 = row0 - b0*NN;
            #pragma unroll
            for (int r = 0; r < 4; r++) {
                bA[r] = b0; nA[r] = n0;
                n0++; if (n0 == NN) { n0 = 0; b0++; }
            }
        }
        #pragma unroll
        for (int ni = 0; ni < 4; ni++) {
            int col = bn + wn*64 + ni*16 + mrow;
            float bv = (EPI == 2) ? bias[col] : 0.f;
            #pragma unroll
            for (int r = 0; r < 4; r++) {
                int row = row0 + r;
                if (row >= M) continue;
                float v = acc[mi][ni][r] + bv;
                if (EPI == 2) {
                    // tanh-form GELU via hw exp (err ~3e-4, < bf16 grain)
                    v = v / (1.0f + __expf(-1.5957691216f*v*(1.0f + 0.044715f*v*v)));
                    Cb[(size_t)row*Nd + col] = f2bf(v);
                } else if (EPI == 5) {
                    Cfz[(size_t)row*Nd + col] = v;
                } else if (EPI == 4) {
                    int sel = col / CC;
                    int rem = col - sel*CC;
                    int h = rem >> 6, d = rem & 63;
                    int bh = bA[r]*HH + h;
                    unsigned short val = f2bf(v);
                    if (sel < 2)
                        Cb[((size_t)sel*BHH + bh)*NN*DD + (size_t)nA[r]*DD + d] = val;
                    else
                        Cb[(size_t)2*BHH*NN*DD + (size_t)bh*DD*NP + (size_t)d*NP + nA[r]] = val;
                }
            }
        }
    }
}

// ---------------------------------------------------------------------------
// Fused qk + fc + LN + softmax -> PT.
// 8 waves (512 thr), 128 S-rows per block, grid (2, BHH): the K panel and the
// fc_wt chunks are staged ONCE per 128 rows (was per 64), halving redundant
// staging traffic and barrier cost per row. Resident waves/CU unchanged
// (was 2 blocks x 4 waves; now 1 block x 8 -- LDS 103 KB).
// XOR swizzles on Ks (row&7, kills the measured 16-way conflict) and Bs.
__global__ __launch_bounds__(512) void attn_score(
    const unsigned short* __restrict__ qb,   // [bh][NN][DD]
    const unsigned short* __restrict__ kb,   // [bh][NN][DD]
    const unsigned short* __restrict__ fw,   // fc_wt [KWW][NP] (k-pad zero)
    const float* __restrict__ fbias,         // fc_b
    const float* __restrict__ g, const float* __restrict__ be,  // attn LN
    unsigned short* __restrict__ PT)         // [bh][NP][NP]
{
    int bh = blockIdx.y;
    int bm = blockIdx.x * 128;
    __shared__ unsigned short Ks[224*DD];    // 28 KB
    __shared__ unsigned short S1s[128*SLS];  // 58 KB
    __shared__ unsigned short Bs[224*32];    // 14 KB
    __shared__ float gls[NP], bls[NP], bbs[NP];
    int tid = threadIdx.x;
    if (tid < NP) {
        bool vc = tid < KWW;
        gls[tid] = vc ? g[tid]     : 1.f;
        bls[tid] = vc ? be[tid]    : 0.f;
        bbs[tid] = vc ? fbias[tid] : 0.f;
    }
    int wv = tid >> 6, lane = tid & 63;      // wv in 0..7
    int quad = lane >> 4, mrow = lane & 15;

    // stage K: 28 groups of 8 rows over 8 waves, inverse-swizzled source col.
    // (rows >= NN read adjacent-buffer bf16 garbage -> finite; those S cols
    //  are multiplied by fc_wt's ZERO k-pad rows in phase 2, so no effect.)
    {
        int lrow = lane >> 3, lsl = lane & 7;
        #pragma unroll
        for (int i = 0; i < 4; i++) {
            int grp = wv + i*8;
            if (grp < 28) {
                int r = grp*8 + lrow;
                int lko = (lsl ^ (r & 7)) * 8;
                __builtin_amdgcn_global_load_lds(
                    (const __attribute__((address_space(1))) void*)(kb + ((size_t)bh*NN + r)*DD + lko),
                    (__attribute__((address_space(3))) void*)(Ks + (size_t)grp*8*DD),
                    16, 0, 0);
            }
        }
    }
    // Q A-fragments straight from global (own 16 rows per wave)
    int qrow = bm + wv*16 + mrow; if (qrow > NN-1) qrow = NN-1;
    short8 aq0 = *(const short8*)&qb[((size_t)bh*NN + qrow)*DD + quad*8];
    short8 aq1 = *(const short8*)&qb[((size_t)bh*NN + qrow)*DD + 32 + quad*8];
    __syncthreads();

    // phase 1 MFMA: acc[ni] = Q(16 rows) x K(cols ni*16..), swizzled Ks reads
    #pragma unroll
    for (int ni = 0; ni < 14; ni++) {
        floatx4 a = (floatx4){0.f,0.f,0.f,0.f};
        int lr = ni*16 + mrow;
        short8 bf0 = *(const short8*)&Ks[(size_t)lr*DD + ((quad    ) ^ (lr & 7))*8];
        short8 bf1 = *(const short8*)&Ks[(size_t)lr*DD + ((4 + quad) ^ (lr & 7))*8];
        a = __builtin_amdgcn_mfma_f32_16x16x32_bf16(aq0, bf0, a, 0, 0, 0);
        a = __builtin_amdgcn_mfma_f32_16x16x32_bf16(aq1, bf1, a, 0, 0, 0);
        // C layout: row = wv*16 + quad*4 + r, col = ni*16 + mrow
        #pragma unroll
        for (int r = 0; r < 4; r++)
            S1s[(size_t)(wv*16 + quad*4 + r)*SLS + ni*16 + mrow] = f2bf(a[r]*0.125f);
    }
    __syncthreads();

    // phase 2: S2 = S1 @ fc_w (fw staged chunk-wise into Bs, swizzled;
    // 14 chunks over 8 waves per k0)
    floatx4 acc[14];
    #pragma unroll
    for (int j = 0; j < 14; j++) acc[j] = (floatx4){0.f,0.f,0.f,0.f};
    for (int k0 = 0; k0 < 7; k0++) {
        for (int c = wv; c < 14; c += 8) {
            int r_ = c*16 + (lane >> 2);
            int gr = r_; if (gr > KWW-1) gr = KWW-1;
            int sl = ((lane & 3) ^ (r_ & 3)) * 8;
            __builtin_amdgcn_global_load_lds(
                (const __attribute__((address_space(1))) void*)(fw + (size_t)gr*NP + k0*32 + sl),
                (__attribute__((address_space(3))) void*)(Bs + (size_t)(c*16)*32),
                16, 0, 0);
        }
        __syncthreads();
        short8 af = *(const short8*)&S1s[(size_t)(wv*16 + mrow)*SLS + k0*32 + quad*8];
        #pragma unroll
        for (int ni = 0; ni < 14; ni++) {
            int lr = ni*16 + mrow;
            short8 bf = *(const short8*)&Bs[(size_t)lr*32 + (quad ^ (lr & 3))*8];
            acc[ni] = __builtin_amdgcn_mfma_f32_16x16x32_bf16(af, bf, acc[ni], 0, 0, 0);
        }
        __syncthreads();
    }

    // epilogue: +bias, row LN, softmax, transposed store (per-wave, 16 rows)
    float s[4] = {}, q[4] = {};
    #pragma unroll
    for (int ni = 0; ni < 14; ni++) {
        int col = ni*16 + mrow;
        float cm = (col < KWW) ? 1.f : 0.f;
        #pragma unroll
        for (int r = 0; r < 4; r++) {
            float x = acc[ni][r] + bbs[col];
            acc[ni][r] = x;
            s[r] += x*cm; q[r] += x*x*cm;
        }
    }
    #pragma unroll
    for (int o = 1; o < 16; o <<= 1)
        #pragma unroll
        for (int r = 0; r < 4; r++) {
            s[r] += __shfl_xor(s[r], o, 64);
            q[r] += __shfl_xor(q[r], o, 64);
        }
    float mu[4], rs[4], mx[4];
    #pragma unroll
    for (int r = 0; r < 4; r++) {
        mu[r] = s[r] * (1.0f/KWW);
        float var = q[r] * (1.0f/KWW) - mu[r]*mu[r];
        rs[r] = rsqrtf(var + 1e-5f);
        mx[r] = -1e30f;
    }
    #pragma unroll
    for (int ni = 0; ni < 14; ni++) {
        int col = ni*16 + mrow;
        bool vc = col < KWW;
        #pragma unroll
        for (int r = 0; r < 4; r++) {
            float x = (acc[ni][r] - mu[r]) * rs[r] * gls[col] + bls[col];
            acc[ni][r] = x;
            if (vc) mx[r] = fmaxf(mx[r], x);
        }
    }
    #pragma unroll
    for (int o = 1; o < 16; o <<= 1)
        #pragma unroll
        for (int r = 0; r < 4; r++)
            mx[r] = fmaxf(mx[r], __shfl_xor(mx[r], o, 64));
    float se[4] = {};
    #pragma unroll
    for (int ni = 0; ni < 14; ni++) {
        int col = ni*16 + mrow;
        float cm = (col < KWW) ? 1.f : 0.f;
        #pragma unroll
        for (int r = 0; r < 4; r++) {
            float p = __expf(acc[ni][r] - mx[r]) * cm;
            acc[ni][r] = p;
            se[r] += p;
        }
    }
    #pragma unroll
    for (int o = 1; o < 16; o <<= 1)
        #pragma unroll
        for (int r = 0; r < 4; r++)
            se[r] += __shfl_xor(se[r], o, 64);
    unsigned short* Pb = PT + (size_t)bh*NP*NP;
    int row0 = bm + wv*16 + quad*4;
    float inv0 = 1.0f/se[0], inv1 = 1.0f/se[1], inv2 = 1.0f/se[2], inv3 = 1.0f/se[3];
    #pragma unroll
    for (int ni = 0; ni < 14; ni++) {
        int col = ni*16 + mrow;
        if (col >= KWW) continue;
        if (row0 + 3 < NN) {
            us4 o = { f2bf(acc[ni][0]*inv0), f2bf(acc[ni][1]*inv1),
                      f2bf(acc[ni][2]*inv2), f2bf(acc[ni][3]*inv3) };
            *(us4*)&Pb[(size_t)col*NP + row0] = o;
        } else {
            float invs[4] = {inv0, inv1, inv2, inv3};
            #pragma unroll
            for (int r = 0; r < 4; r++)
                if (row0 + r < NN)
                    Pb[(size_t)col*NP + row0 + r] = f2bf(acc[ni][r]*invs[r]);
        }
    }
}

// ---------------------------------------------------------------------------
// Fused yv + fc2. Grid (2, BHH): each block handles TWO d-tiles, so every Pb
// and fw fragment load feeds 2 MFMAs (halves redundant L2 reads, doubles ILP).
__global__ __launch_bounds__(256) void attn_out2(
    const unsigned short* __restrict__ PT,   // [bh][NP][NP]
    const unsigned short* __restrict__ vT,   // [bh][DD][NP] (n-pad zeroed)
    const unsigned short* __restrict__ fw,   // fc2_wt [NP][NP] (pad rows/cols zero)
    const float* __restrict__ bias,          // fc2_b [197]
    float* __restrict__ x1)
{
    int dt0 = blockIdx.x * 2;            // d-tiles {dt0, dt0+1}
    int bh = blockIdx.y; int b = bh / HH, h = bh - b*HH;
    __shared__ unsigned short yT[32*232];    // [dd*16 + d][kw]
    int wv = threadIdx.x >> 6, lane = threadIdx.x & 63;
    int quad = lane >> 4, mrow = lane & 15;
    const unsigned short* Pb = PT + (size_t)bh*NP*NP;
    const unsigned short* Vb = vT + (size_t)bh*DD*NP + (size_t)(dt0*16)*NP;

    short8 bv0[7], bv1[7];
    #pragma unroll
    for (int kc = 0; kc < 7; kc++) {
        bv0[kc] = *(const short8*)&Vb[(size_t)mrow*NP + kc*32 + quad*8];
        bv1[kc] = *(const short8*)&Vb[(size_t)(16 + mrow)*NP + kc*32 + quad*8];
    }
    // Stage A: 14 kw-tiles over 4 waves; each Pb fragment used by both d-tiles
    #pragma unroll
    for (int i = 0; i < 4; i++) {
        int t0 = wv + i*4;
        if (t0 < 14) {
            floatx4 a0 = (floatx4){0.f,0.f,0.f,0.f};
            floatx4 a1 = (floatx4){0.f,0.f,0.f,0.f};
            #pragma unroll
            for (int kc = 0; kc < 7; kc++) {
                short8 p0 = *(const short8*)&Pb[(size_t)(t0*16 + mrow)*NP + kc*32 + quad*8];
                a0 = __builtin_amdgcn_mfma_f32_16x16x32_bf16(p0, bv0[kc], a0, 0, 0, 0);
                a1 = __builtin_amdgcn_mfma_f32_16x16x32_bf16(p0, bv1[kc], a1, 0, 0, 0);
            }
            us4 o0 = { f2bf(a0[0]), f2bf(a0[1]), f2bf(a0[2]), f2bf(a0[3]) };
            us4 o1 = { f2bf(a1[0]), f2bf(a1[1]), f2bf(a1[2]), f2bf(a1[3]) };
            *(us4*)&yT[(size_t)mrow*232 + t0*16 + quad*4] = o0;
            *(us4*)&yT[(size_t)(16 + mrow)*232 + t0*16 + quad*4] = o1;
        }
    }
    __syncthreads();

    short8 yf0[7], yf1[7];
    #pragma unroll
    for (int kc = 0; kc < 7; kc++) {
        yf0[kc] = *(const short8*)&yT[(size_t)mrow*232 + kc*32 + quad*8];
        yf1[kc] = *(const short8*)&yT[(size_t)(16 + mrow)*232 + kc*32 + quad*8];
    }
    float* xb = x1 + (size_t)b*NN*CC + (size_t)h*DD + dt0*16 + mrow;
    // Stage B: 13 n-tiles over 4 waves; each fw fragment used by both d-tiles
    #pragma unroll
    for (int i = 0; i < 4; i++) {
        int n0t = wv + i*4;
        if (n0t < 13) {
            floatx4 a0 = (floatx4){0.f,0.f,0.f,0.f};
            floatx4 a1 = (floatx4){0.f,0.f,0.f,0.f};
            #pragma unroll
            for (int kc = 0; kc < 7; kc++) {
                short8 f0 = *(const short8*)&fw[(size_t)(n0t*16 + mrow)*NP + kc*32 + quad*8];
                a0 = __builtin_amdgcn_mfma_f32_16x16x32_bf16(f0, yf0[kc], a0, 0, 0, 0);
                a1 = __builtin_amdgcn_mfma_f32_16x16x32_bf16(f0, yf1[kc], a1, 0, 0, 0);
            }
            #pragma unroll
            for (int r = 0; r < 4; r++) {
                int n = n0t*16 + quad*4 + r;
                if (n < NN) {
                    xb[(size_t)n*CC]      += a0[r] + bias[n];
                    xb[(size_t)n*CC + 16] += a1[r] + bias[n];
                }
            }
        }
    }
}

// ---------------------------------------------------------------------------
extern "C" void kernel_launch(void* const* d_in, const int* in_sizes, int n_in,
                              void* d_out, int out_size, void* d_ws, size_t ws_size,
                              hipStream_t stream) {
    const float* x     = (const float*)d_in[0];
    const float* qkv_w = (const float*)d_in[1];
    const float* fc_w  = (const float*)d_in[2];
    const float* fc_b  = (const float*)d_in[3];
    const float* alng  = (const float*)d_in[4];
    const float* alnb  = (const float*)d_in[5];
    const float* fc2w  = (const float*)d_in[6];
    const float* fc2b  = (const float*)d_in[7];
    const float* w1    = (const float*)d_in[8];
    const float* b1    = (const float*)d_in[9];
    const float* w2    = (const float*)d_in[10];
    const float* b2    = (const float*)d_in[11];
    const float* flng  = (const float*)d_in[12];
    const float* flnb  = (const float*)d_in[13];
    const float* glng  = (const float*)d_in[14];
    const float* glnb  = (const float*)d_in[15];
    float* out = (float*)d_out;

    float* ws = (float*)d_ws;
    size_t off = 0;
    float* x1 = ws + off; off += (size_t)RR*CC;
    float* x2 = ws + off; off += (size_t)RR*CC;
    float* part = ws + off; off += (size_t)2*RR*CC;     // MLP2 split-K partials
    unsigned short* lnb = (unsigned short*)(ws + off); off += (size_t)RR*CC/2;
    // qkv bf16 region: q[bh][n][64], k[bh][n][64], vT[bh][64][NP]
    unsigned short* qkvo = (unsigned short*)(ws + off);
    unsigned short* qb = qkvo;
    unsigned short* kb = qkvo + (size_t)BHH*NN*DD;
    unsigned short* vT = qkvo + (size_t)2*BHH*NN*DD;
    off += ((size_t)2*BHH*NN*DD + (size_t)BHH*DD*NP + 1) / 2;
    unsigned short* PT   = (unsigned short*)(ws + off); off += (size_t)BHH*NP*NP/2;
    unsigned short* hid  = (unsigned short*)(ws + off); off += (size_t)RR*HIDD/2;
    unsigned short* qkv_wt = (unsigned short*)(ws + off); off += (size_t)3*CC*CC/2;
    unsigned short* w1t    = (unsigned short*)(ws + off); off += (size_t)CC*HIDD/2;
    unsigned short* w2t    = (unsigned short*)(ws + off); off += (size_t)CC*HIDD/2;
    unsigned short* fc_wt  = (unsigned short*)(ws + off); off += (size_t)NP*NP/2 + 16;
    unsigned short* fc2_wt = (unsigned short*)(ws + off); off += (size_t)NP*NP/2 + 16;

    // Zero pads: vT (n-pad cols must be 0), fc_wt/fc2_wt (pad rows/cols).
    hipMemsetAsync(vT, 0, (size_t)BHH*DD*NP*2, stream);
    hipMemsetAsync(fc_wt, 0, (size_t)NP*NP*2, stream);
    hipMemsetAsync(fc2_wt, 0, (size_t)NP*NP*2, stream);

    // Weight prep: bf16 transposed (+padded) copies, once per launch.
    transpose_cast<<<dim3(72, 24), 256, 0, stream>>>(qkv_w, qkv_wt, CC, 3*CC, CC);
    transpose_cast<<<dim3(96, 24), 256, 0, stream>>>(w1, w1t, CC, HIDD, CC);
    transpose_cast<<<dim3(24, 96), 256, 0, stream>>>(w2, w2t, HIDD, CC, HIDD);
    transpose_cast<<<dim3(7, 7),   256, 0, stream>>>(fc_w,  fc_wt,  NN, KWW, NP);
    transpose_cast<<<dim3(7, 7),   256, 0, stream>>>(fc2w,  fc2_wt, KWW, NN, NP);

    // init x1=x2=x fused with layer-0 f-LN -> lnb
    init_ln<<<RR, 192, 0, stream>>>(x, x1, x2, flng, flnb, lnb);

    const int MT = (RR + 127) / 128;   // 50 row-tiles
    for (int l = 0; l < NL; l++) {
        // --- attention branch: y1 = x1 + attn(LN(x2)) ---  (lnb holds f-LN(x2))
        gemm128<4,1><<<dim3(3*CC/128, MT), 256, 0, stream>>>(
            lnb, qkv_wt, nullptr, nullptr, qb, RR, 3*CC, CC);
        // fused qk + fc + LN + softmax -> PT (8 waves, 128 rows/block)
        attn_score<<<dim3(2, BHH), 512, 0, stream>>>(
            qb, kb, fc_wt, fc_b, alng, alnb, PT);
        // fused yv + fc2 -> x1 += (2 d-tiles per block)
        attn_out2<<<dim3(2, BHH), 256, 0, stream>>>(PT, vT, fc2_wt, fc2b, x1);
        // --- mlp branch: y2 = x2 + mlp(LN(y1)) ---
        ln768_kernel<<<RR, 192, 0, stream>>>(x1, glng + l*CC, glnb + l*CC, lnb);
        gemm128<2,1><<<dim3(HIDD/128, MT), 256, 0, stream>>>(
            lnb, w1t, b1, nullptr, hid, RR, HIDD, CC);
        // MLP2: split-K=2, 6 x 50 x 2 = 600 blocks
        gemm128<5,2><<<dim3(CC/128, MT, 2), 256, 0, stream>>>(
            hid, w2t, nullptr, part, nullptr, RR, CC, HIDD);
        // x2 += part0+part1+b2; mode 1 = fuse next layer f-LN; mode 2 (last) =
        // final output 0.5*(x1+x2new) written directly to out.
        if (l + 1 < NL) {
            reduce_ln<<<RR, 192, 0, stream>>>(
                x2, part, b2, flng + (l+1)*CC, flnb + (l+1)*CC, lnb,
                nullptr, nullptr, 1);
        } else {
            reduce_ln<<<RR, 192, 0, stream>>>(
                x2, part, b2, nullptr, nullptr, nullptr, x1, out, 2);
        }
    }
}

// Round 12
// 3059.501 us; speedup vs baseline: 1.0504x; 1.0504x over previous
//
#include <hip/hip_runtime.h>
#include <math.h>

// Problem constants
#define BB   32
#define NN   197
#define CC   768
#define HH   12
#define DD   64
#define KWW  197
#define HIDD 3072
#define NL   12
#define RR   (BB*NN)      // 6304 rows
#define BHH  (BB*HH)      // 384 batch*head
#define NP   224          // n/kw padded to multiple of 32 (for MFMA K dim)
#define SLS  232          // S1s LDS row stride (bank spread)

typedef __attribute__((ext_vector_type(8))) short short8;
typedef __attribute__((ext_vector_type(4))) float floatx4;
typedef __attribute__((ext_vector_type(4))) unsigned short us4;

__device__ __forceinline__ unsigned short f2bf(float f) {
    unsigned int u = __float_as_uint(f);
    u += 0x7fff + ((u >> 16) & 1);          // round-to-nearest-even
    return (unsigned short)(u >> 16);
}

// ---------------------------------------------------------------------------
// LayerNorm over C=768 -> bf16 output. One block (192 thr) per row, float4.
__global__ void ln768_kernel(const float* __restrict__ in, const float* __restrict__ g,
                             const float* __restrict__ be, unsigned short* __restrict__ out) {
    int row = blockIdx.x;
    int t = threadIdx.x;                 // 0..191
    float4 v = ((const float4*)(in + (size_t)row * CC))[t];
    float s = v.x+v.y+v.z+v.w;
    float q = v.x*v.x+v.y*v.y+v.z*v.z+v.w*v.w;
    for (int off = 1; off < 64; off <<= 1) {
        s += __shfl_xor(s, off, 64);
        q += __shfl_xor(q, off, 64);
    }
    __shared__ float sh[6];
    int wv = t >> 6, ln = t & 63;
    if (ln == 0) { sh[wv] = s; sh[3+wv] = q; }
    __syncthreads();
    s = sh[0]+sh[1]+sh[2];
    q = sh[3]+sh[4]+sh[5];
    float mu  = s * (1.0f/CC);
    float var = q * (1.0f/CC) - mu*mu;
    float rs  = rsqrtf(var + 1e-5f);
    float4 gv = ((const float4*)g)[t];
    float4 bv = ((const float4*)be)[t];
    us4 o = { f2bf((v.x-mu)*rs*gv.x + bv.x), f2bf((v.y-mu)*rs*gv.y + bv.y),
              f2bf((v.z-mu)*rs*gv.z + bv.z), f2bf((v.w-mu)*rs*gv.w + bv.w) };
    *(us4*)(out + (size_t)row*CC + t*4) = o;
}

// ---------------------------------------------------------------------------
// Fused init: x1 = x2 = x, and LN(x) -> lnb (layer-0 f-LN). 192 thr, float4.
__global__ void init_ln(const float* __restrict__ x, float* __restrict__ x1,
                        float* __restrict__ x2,
                        const float* __restrict__ g, const float* __restrict__ be,
                        unsigned short* __restrict__ out) {
    int row = blockIdx.x;
    int t = threadIdx.x;
    float4 v = ((const float4*)(x + (size_t)row * CC))[t];
    ((float4*)(x1 + (size_t)row * CC))[t] = v;
    ((float4*)(x2 + (size_t)row * CC))[t] = v;
    float s = v.x+v.y+v.z+v.w;
    float q = v.x*v.x+v.y*v.y+v.z*v.z+v.w*v.w;
    for (int off = 1; off < 64; off <<= 1) {
        s += __shfl_xor(s, off, 64);
        q += __shfl_xor(q, off, 64);
    }
    __shared__ float sh[6];
    int wv = t >> 6, ln = t & 63;
    if (ln == 0) { sh[wv] = s; sh[3+wv] = q; }
    __syncthreads();
    s = sh[0]+sh[1]+sh[2];
    q = sh[3]+sh[4]+sh[5];
    float mu  = s * (1.0f/CC);
    float var = q * (1.0f/CC) - mu*mu;
    float rs  = rsqrtf(var + 1e-5f);
    float4 gv = ((const float4*)g)[t];
    float4 bv = ((const float4*)be)[t];
    us4 o = { f2bf((v.x-mu)*rs*gv.x + bv.x), f2bf((v.y-mu)*rs*gv.y + bv.y),
              f2bf((v.z-mu)*rs*gv.z + bv.z), f2bf((v.w-mu)*rs*gv.w + bv.w) };
    *(us4*)(out + (size_t)row*CC + t*4) = o;
}

// ---------------------------------------------------------------------------
// Fused: x2 += part0 + part1 + b2; then
//   mode 1: LN(x2_new) -> out (next layer f-LN)
//   mode 2: final output: outf = 0.5*(x1 + x2_new)
// 192 threads per row, float4 path.
__global__ void reduce_ln(float* __restrict__ x2, const float* __restrict__ part,
                          const float* __restrict__ b2,
                          const float* __restrict__ g, const float* __restrict__ be,
                          unsigned short* __restrict__ out,
                          const float* __restrict__ x1f, float* __restrict__ outf,
                          int mode) {
    int row = blockIdx.x;
    int t = threadIdx.x;
    float4 v  = ((float4*)(x2 + (size_t)row * CC))[t];
    float4 a0 = ((const float4*)(part + (size_t)row * CC))[t];
    float4 a1 = ((const float4*)(part + (size_t)RR*CC + (size_t)row * CC))[t];
    float4 bb = ((const float4*)b2)[t];
    v.x += a0.x + a1.x + bb.x;
    v.y += a0.y + a1.y + bb.y;
    v.z += a0.z + a1.z + bb.z;
    v.w += a0.w + a1.w + bb.w;
    ((float4*)(x2 + (size_t)row * CC))[t] = v;
    if (mode == 2) {
        float4 xo = ((const float4*)(x1f + (size_t)row * CC))[t];
        float4 o;
        o.x = 0.5f*(xo.x + v.x); o.y = 0.5f*(xo.y + v.y);
        o.z = 0.5f*(xo.z + v.z); o.w = 0.5f*(xo.w + v.w);
        ((float4*)(outf + (size_t)row * CC))[t] = o;
        return;
    }
    float s = v.x+v.y+v.z+v.w;
    float q = v.x*v.x+v.y*v.y+v.z*v.z+v.w*v.w;
    for (int off = 1; off < 64; off <<= 1) {
        s += __shfl_xor(s, off, 64);
        q += __shfl_xor(q, off, 64);
    }
    __shared__ float sh[6];
    int wv = t >> 6, ln = t & 63;
    if (ln == 0) { sh[wv] = s; sh[3+wv] = q; }
    __syncthreads();
    s = sh[0]+sh[1]+sh[2];
    q = sh[3]+sh[4]+sh[5];
    float mu  = s * (1.0f/CC);
    float var = q * (1.0f/CC) - mu*mu;
    float rs  = rsqrtf(var + 1e-5f);
    float4 gv = ((const float4*)g)[t];
    float4 bv = ((const float4*)be)[t];
    us4 o = { f2bf((v.x-mu)*rs*gv.x + bv.x), f2bf((v.y-mu)*rs*gv.y + bv.y),
              f2bf((v.z-mu)*rs*gv.z + bv.z), f2bf((v.w-mu)*rs*gv.w + bv.w) };
    *(us4*)(out + (size_t)row*CC + t*4) = o;
}

// ---------------------------------------------------------------------------
// Transpose + cast fp32 [K][Nd] -> bf16 [Nd][Kpad], zero-filling k in [K,Kpad).
__global__ void transpose_cast(const float* __restrict__ in, unsigned short* __restrict__ out,
                               int K, int Nd, int Kpad) {
    __shared__ float tile[32][33];
    int n0 = blockIdx.x*32, k0 = blockIdx.y*32;
    int tx = threadIdx.x & 31, ty = threadIdx.x >> 5;   // 32 x 8
    #pragma unroll
    for (int i = 0; i < 4; i++) {
        int k = k0 + ty + i*8;
        tile[ty + i*8][tx] = (k < K && n0+tx < Nd) ? in[(size_t)k*Nd + n0 + tx] : 0.f;
    }
    __syncthreads();
    #pragma unroll
    for (int i = 0; i < 4; i++) {
        int n = n0 + ty + i*8;
        if (n < Nd && k0 + tx < Kpad) out[(size_t)n*Kpad + k0 + tx] = f2bf(tile[tx][ty + i*8]);
    }
}

// ---------------------------------------------------------------------------
// bf16 MFMA GEMM: C = A(bf16,[M][K]) @ Bt(bf16,[Nd][K])^T.
// 128x128 tile, BK=64, 256 thr (4 waves, 2x2), single-buffer 2-barrier loop.
// Proven plateau for this problem's shapes: 0 bank conflicts. Prefetch
// restructurings all regressed (r1/r2/r4/r9) - arm closed.
//  - LDS XOR swizzle: phys 16B slot = logical ^ (row&7); inverse permutation
//    applied to per-lane GLOBAL source column; reads XOR back.
//  - Bijective XCD-aware blockIdx remap (m204) + 8-row SUPERTILE banding:
//    without banding each XCD chunk spans few bm x ALL bn -> full B panel
//    refetched per XCD (measured 43 MB vs ~14 ideal). Banding makes chunks
//    ~8x14 2D patches -> per-XCD fetch ~ (8+14) tiles instead of (6+24).
// EPI: 2 = +bias fast-GELU store bf16; 4 = QKV scatter; 5 = fp32 split-K partial.
template<int EPI, int KS>
__global__ __launch_bounds__(256) void gemm128(
    const unsigned short* __restrict__ A, const unsigned short* __restrict__ Bt,
    const float* __restrict__ bias, float* __restrict__ Cf, unsigned short* __restrict__ Cb,
    int M, int Nd, int K)
{
    __shared__ unsigned short As[128*64];   // 16 KiB, [row][64 cols], 128B rows
    __shared__ unsigned short Bs[128*64];   // 16 KiB
    int tid  = threadIdx.x;
    int wv   = tid >> 6, lane = tid & 63;
    int wm   = wv >> 1, wn = wv & 1;
    int quad = lane >> 4, mrow = lane & 15;
    int rl   = lane >> 3, ps = lane & 7;    // staging: 8 lanes/row, 16B each

    // XCD-aware bijective chunked remap (m204)
    int gx   = gridDim.x, gy = gridDim.y;
    int nwg  = gx * gy;
    int orig = blockIdx.y * gx + blockIdx.x;
    int qq = nwg >> 3, rr = nwg & 7;
    int xcd = orig & 7, idx = orig >> 3;
    int wg  = (xcd < rr ? xcd*(qq+1) : rr*(qq+1) + (xcd-rr)*qq) + idx;
    // 8-row supertile banding (bijective: only the last band can be partial)
    const int SH = 8;
    int g2   = SH * gx;
    int band = wg / g2;
    int remn = wg - band * g2;
    int rowsLeft = gy - band * SH;
    int SHe  = rowsLeft < SH ? rowsLeft : SH;
    int bn   = (remn / SHe) * 128;
    int bm   = (band * SH + remn % SHe) * 128;

    const int Kc    = K / KS;
    const int kbase = (KS > 1) ? blockIdx.z * Kc : 0;

    floatx4 acc[4][4];
    #pragma unroll
    for (int i = 0; i < 4; i++)
        #pragma unroll
        for (int j = 0; j < 4; j++) acc[i][j] = (floatx4){0.f,0.f,0.f,0.f};

    for (int k0 = kbase; k0 < kbase + Kc; k0 += 64) {
        // stage A rows [wv*32, wv*32+32): 4 issues x 8 rows, inverse-swz source
        #pragma unroll
        for (int i = 0; i < 4; i++) {
            int r_ = wv*32 + i*8 + rl;
            int sl = ps ^ (r_ & 7);
            int gr = bm + r_; if (gr > M-1) gr = M-1;
            __builtin_amdgcn_global_load_lds(
                (const __attribute__((address_space(1))) void*)(A + (size_t)gr*K + k0 + sl*8),
                (__attribute__((address_space(3))) void*)(As + (wv*32 + i*8)*64),
                16, 0, 0);
        }
        #pragma unroll
        for (int i = 0; i < 4; i++) {
            int r_ = wv*32 + i*8 + rl;
            int sl = ps ^ (r_ & 7);
            int gr = bn + r_;
            __builtin_amdgcn_global_load_lds(
                (const __attribute__((address_space(1))) void*)(Bt + (size_t)gr*K + k0 + sl*8),
                (__attribute__((address_space(3))) void*)(Bs + (wv*32 + i*8)*64),
                16, 0, 0);
        }
        __syncthreads();
        #pragma unroll
        for (int kk = 0; kk < 2; kk++) {
            short8 af[4], bf[4];
            #pragma unroll
            for (int mi = 0; mi < 4; mi++) {
                int lr = wm*64 + mi*16 + mrow;
                af[mi] = *(const short8*)&As[lr*64 + (((kk<<2)|quad) ^ (lr & 7))*8];
            }
            #pragma unroll
            for (int ni = 0; ni < 4; ni++) {
                int lr = wn*64 + ni*16 + mrow;
                bf[ni] = *(const short8*)&Bs[lr*64 + (((kk<<2)|quad) ^ (lr & 7))*8];
            }
            #pragma unroll
            for (int mi = 0; mi < 4; mi++)
                #pragma unroll
                for (int ni = 0; ni < 4; ni++)
                    acc[mi][ni] = __builtin_amdgcn_mfma_f32_16x16x32_bf16(
                        af[mi], bf[ni], acc[mi][ni], 0, 0, 0);
        }
        __syncthreads();
    }

    // ---- epilogue
    float* Cfz = (EPI == 5) ? (Cf + (size_t)blockIdx.z * M * Nd) : Cf;
    #pragma unroll
    for (int mi = 0; mi < 4; mi++) {
        int row0 = bm + wm*64 + mi*16 + quad*4;
        // EPI==4: precompute b,n per r (hoists row/NN out of the ni loop)
        int bA[4], nA[4];
        if (EPI == 4) {
            int b0 = row0 / NN, n0 = row0 - b0*NN;
            #pragma unroll
            for (int r = 0; r < 4; r++) {
                bA[r] = b0; nA[r] = n0;
                n0++; if (n0 == NN) { n0 = 0; b0++; }
            }
        }
        #pragma unroll
        for (int ni = 0; ni < 4; ni++) {
            int col = bn + wn*64 + ni*16 + mrow;
            float bv = (EPI == 2) ? bias[col] : 0.f;
            #pragma unroll
            for (int r = 0; r < 4; r++) {
                int row = row0 + r;
                if (row >= M) continue;
                float v = acc[mi][ni][r] + bv;
                if (EPI == 2) {
                    // tanh-form GELU via hw exp (err ~3e-4, < bf16 grain)
                    v = v / (1.0f + __expf(-1.5957691216f*v*(1.0f + 0.044715f*v*v)));
                    Cb[(size_t)row*Nd + col] = f2bf(v);
                } else if (EPI == 5) {
                    Cfz[(size_t)row*Nd + col] = v;
                } else if (EPI == 4) {
                    int sel = col / CC;
                    int rem = col - sel*CC;
                    int h = rem >> 6, d = rem & 63;
                    int bh = bA[r]*HH + h;
                    unsigned short val = f2bf(v);
                    if (sel < 2)
                        Cb[((size_t)sel*BHH + bh)*NN*DD + (size_t)nA[r]*DD + d] = val;
                    else
                        Cb[(size_t)2*BHH*NN*DD + (size_t)bh*DD*NP + (size_t)d*NP + nA[r]] = val;
                }
            }
        }
    }
}

// ---------------------------------------------------------------------------
// Fused qk + fc + LN + softmax -> PT  (round-10 proven version: 4 waves,
// 64 rows/block, staged phase 2 + XOR swizzles on Ks/Bs).
// Grid (4, BHH); block = 4 waves; row tile bm = blockIdx.x*64 (rows of S).
__global__ __launch_bounds__(256) void attn_score(
    const unsigned short* __restrict__ qb,   // [bh][NN][DD]
    const unsigned short* __restrict__ kb,   // [bh][NN][DD]
    const unsigned short* __restrict__ fw,   // fc_wt [KWW][NP] (k-pad zero)
    const float* __restrict__ fbias,         // fc_b
    const float* __restrict__ g, const float* __restrict__ be,  // attn LN
    unsigned short* __restrict__ PT)         // [bh][NP][NP]
{
    int bh = blockIdx.y;
    int bm = blockIdx.x * 64;
    __shared__ unsigned short Ks[224*DD];    // 28 KB
    __shared__ unsigned short S1s[64*SLS];   // 29 KB
    __shared__ unsigned short Bs[224*32];    // 14 KB
    __shared__ float gls[NP], bls[NP], bbs[NP];
    int tid = threadIdx.x;
    if (tid < NP) {
        bool vc = tid < KWW;
        gls[tid] = vc ? g[tid]     : 1.f;
        bls[tid] = vc ? be[tid]    : 0.f;
        bbs[tid] = vc ? fbias[tid] : 0.f;
    }
    int wv = tid >> 6, lane = tid & 63;
    int quad = lane >> 4, mrow = lane & 15;

    // stage K rows [wv*56, wv*56+56) -> Ks, inverse-swizzled source column
    {
        int lrow = lane >> 3, lsl = lane & 7;
        #pragma unroll
        for (int i = 0; i < 7; i++) {
            int r = wv*56 + i*8 + lrow;
            int lko = (lsl ^ (r & 7)) * 8;
            __builtin_amdgcn_global_load_lds(
                (const __attribute__((address_space(1))) void*)(kb + ((size_t)bh*NN + r)*DD + lko),
                (__attribute__((address_space(3))) void*)(Ks + (size_t)(wv*56 + i*8)*DD),
                16, 0, 0);
        }
    }
    // Q A-fragments straight from global (own rows only)
    int qrow = bm + wv*16 + mrow; if (qrow > NN-1) qrow = NN-1;
    short8 aq0 = *(const short8*)&qb[((size_t)bh*NN + qrow)*DD + quad*8];
    short8 aq1 = *(const short8*)&qb[((size_t)bh*NN + qrow)*DD + 32 + quad*8];
    __syncthreads();

    // phase 1 MFMA: acc[ni] = Q(16 rows) x K(cols ni*16..), swizzled Ks reads
    #pragma unroll
    for (int ni = 0; ni < 14; ni++) {
        floatx4 a = (floatx4){0.f,0.f,0.f,0.f};
        int lr = ni*16 + mrow;
        short8 bf0 = *(const short8*)&Ks[(size_t)lr*DD + ((quad    ) ^ (lr & 7))*8];
        short8 bf1 = *(const short8*)&Ks[(size_t)lr*DD + ((4 + quad) ^ (lr & 7))*8];
        a = __builtin_amdgcn_mfma_f32_16x16x32_bf16(aq0, bf0, a, 0, 0, 0);
        a = __builtin_amdgcn_mfma_f32_16x16x32_bf16(aq1, bf1, a, 0, 0, 0);
        // C layout: row = wv*16 + quad*4 + r, col = ni*16 + mrow
        #pragma unroll
        for (int r = 0; r < 4; r++)
            S1s[(size_t)(wv*16 + quad*4 + r)*SLS + ni*16 + mrow] = f2bf(a[r]*0.125f);
    }
    __syncthreads();

    // phase 2: S2 = S1 @ fc_w (fw staged chunk-wise into Bs, swizzled)
    floatx4 acc[14];
    #pragma unroll
    for (int j = 0; j < 14; j++) acc[j] = (floatx4){0.f,0.f,0.f,0.f};
    for (int k0 = 0; k0 < 7; k0++) {
        for (int c = wv; c < 14; c += 4) {
            int r_ = c*16 + (lane >> 2);
            int gr = r_; if (gr > KWW-1) gr = KWW-1;
            int sl = ((lane & 3) ^ (r_ & 3)) * 8;
            __builtin_amdgcn_global_load_lds(
                (const __attribute__((address_space(1))) void*)(fw + (size_t)gr*NP + k0*32 + sl),
                (__attribute__((address_space(3))) void*)(Bs + (size_t)(c*16)*32),
                16, 0, 0);
        }
        __syncthreads();
        short8 af = *(const short8*)&S1s[(size_t)(wv*16 + mrow)*SLS + k0*32 + quad*8];
        #pragma unroll
        for (int ni = 0; ni < 14; ni++) {
            int lr = ni*16 + mrow;
            short8 bf = *(const short8*)&Bs[(size_t)lr*32 + (quad ^ (lr & 3))*8];
            acc[ni] = __builtin_amdgcn_mfma_f32_16x16x32_bf16(af, bf, acc[ni], 0, 0, 0);
        }
        __syncthreads();
    }

    // epilogue: +bias, row LN, softmax, transposed store
    float s[4] = {}, q[4] = {};
    #pragma unroll
    for (int ni = 0; ni < 14; ni++) {
        int col = ni*16 + mrow;
        float cm = (col < KWW) ? 1.f : 0.f;
        #pragma unroll
        for (int r = 0; r < 4; r++) {
            float x = acc[ni][r] + bbs[col];
            acc[ni][r] = x;
            s[r] += x*cm; q[r] += x*x*cm;
        }
    }
    #pragma unroll
    for (int o = 1; o < 16; o <<= 1)
        #pragma unroll
        for (int r = 0; r < 4; r++) {
            s[r] += __shfl_xor(s[r], o, 64);
            q[r] += __shfl_xor(q[r], o, 64);
        }
    float mu[4], rs[4], mx[4];
    #pragma unroll
    for (int r = 0; r < 4; r++) {
        mu[r] = s[r] * (1.0f/KWW);
        float var = q[r] * (1.0f/KWW) - mu[r]*mu[r];
        rs[r] = rsqrtf(var + 1e-5f);
        mx[r] = -1e30f;
    }
    #pragma unroll
    for (int ni = 0; ni < 14; ni++) {
        int col = ni*16 + mrow;
        bool vc = col < KWW;
        #pragma unroll
        for (int r = 0; r < 4; r++) {
            float x = (acc[ni][r] - mu[r]) * rs[r] * gls[col] + bls[col];
            acc[ni][r] = x;
            if (vc) mx[r] = fmaxf(mx[r], x);
        }
    }
    #pragma unroll
    for (int o = 1; o < 16; o <<= 1)
        #pragma unroll
        for (int r = 0; r < 4; r++)
            mx[r] = fmaxf(mx[r], __shfl_xor(mx[r], o, 64));
    float se[4] = {};
    #pragma unroll
    for (int ni = 0; ni < 14; ni++) {
        int col = ni*16 + mrow;
        float cm = (col < KWW) ? 1.f : 0.f;
        #pragma unroll
        for (int r = 0; r < 4; r++) {
            float p = __expf(acc[ni][r] - mx[r]) * cm;
            acc[ni][r] = p;
            se[r] += p;
        }
    }
    #pragma unroll
    for (int o = 1; o < 16; o <<= 1)
        #pragma unroll
        for (int r = 0; r < 4; r++)
            se[r] += __shfl_xor(se[r], o, 64);
    unsigned short* Pb = PT + (size_t)bh*NP*NP;
    int row0 = bm + wv*16 + quad*4;
    float inv0 = 1.0f/se[0], inv1 = 1.0f/se[1], inv2 = 1.0f/se[2], inv3 = 1.0f/se[3];
    #pragma unroll
    for (int ni = 0; ni < 14; ni++) {
        int col = ni*16 + mrow;
        if (col >= KWW) continue;
        if (row0 + 3 < NN) {
            us4 o = { f2bf(acc[ni][0]*inv0), f2bf(acc[ni][1]*inv1),
                      f2bf(acc[ni][2]*inv2), f2bf(acc[ni][3]*inv3) };
            *(us4*)&Pb[(size_t)col*NP + row0] = o;
        } else {
            float invs[4] = {inv0, inv1, inv2, inv3};
            #pragma unroll
            for (int r = 0; r < 4; r++)
                if (row0 + r < NN)
                    Pb[(size_t)col*NP + row0 + r] = f2bf(acc[ni][r]*invs[r]);
        }
    }
}

// ---------------------------------------------------------------------------
// Fused yv + fc2. Grid (2, BHH): each block handles TWO d-tiles, so every Pb
// and fw fragment load feeds 2 MFMAs (halves redundant L2 reads, doubles ILP).
__global__ __launch_bounds__(256) void attn_out2(
    const unsigned short* __restrict__ PT,   // [bh][NP][NP]
    const unsigned short* __restrict__ vT,   // [bh][DD][NP] (n-pad zeroed)
    const unsigned short* __restrict__ fw,   // fc2_wt [NP][NP] (pad rows/cols zero)
    const float* __restrict__ bias,          // fc2_b [197]
    float* __restrict__ x1)
{
    int dt0 = blockIdx.x * 2;            // d-tiles {dt0, dt0+1}
    int bh = blockIdx.y; int b = bh / HH, h = bh - b*HH;
    __shared__ unsigned short yT[32*232];    // [dd*16 + d][kw]
    int wv = threadIdx.x >> 6, lane = threadIdx.x & 63;
    int quad = lane >> 4, mrow = lane & 15;
    const unsigned short* Pb = PT + (size_t)bh*NP*NP;
    const unsigned short* Vb = vT + (size_t)bh*DD*NP + (size_t)(dt0*16)*NP;

    short8 bv0[7], bv1[7];
    #pragma unroll
    for (int kc = 0; kc < 7; kc++) {
        bv0[kc] = *(const short8*)&Vb[(size_t)mrow*NP + kc*32 + quad*8];
        bv1[kc] = *(const short8*)&Vb[(size_t)(16 + mrow)*NP + kc*32 + quad*8];
    }
    // Stage A: 14 kw-tiles over 4 waves; each Pb fragment used by both d-tiles
    #pragma unroll
    for (int i = 0; i < 4; i++) {
        int t0 = wv + i*4;
        if (t0 < 14) {
            floatx4 a0 = (floatx4){0.f,0.f,0.f,0.f};
            floatx4 a1 = (floatx4){0.f,0.f,0.f,0.f};
            #pragma unroll
            for (int kc = 0; kc < 7; kc++) {
                short8 p0 = *(const short8*)&Pb[(size_t)(t0*16 + mrow)*NP + kc*32 + quad*8];
                a0 = __builtin_amdgcn_mfma_f32_16x16x32_bf16(p0, bv0[kc], a0, 0, 0, 0);
                a1 = __builtin_amdgcn_mfma_f32_16x16x32_bf16(p0, bv1[kc], a1, 0, 0, 0);
            }
            us4 o0 = { f2bf(a0[0]), f2bf(a0[1]), f2bf(a0[2]), f2bf(a0[3]) };
            us4 o1 = { f2bf(a1[0]), f2bf(a1[1]), f2bf(a1[2]), f2bf(a1[3]) };
            *(us4*)&yT[(size_t)mrow*232 + t0*16 + quad*4] = o0;
            *(us4*)&yT[(size_t)(16 + mrow)*232 + t0*16 + quad*4] = o1;
        }
    }
    __syncthreads();

    short8 yf0[7], yf1[7];
    #pragma unroll
    for (int kc = 0; kc < 7; kc++) {
        yf0[kc] = *(const short8*)&yT[(size_t)mrow*232 + kc*32 + quad*8];
        yf1[kc] = *(const short8*)&yT[(size_t)(16 + mrow)*232 + kc*32 + quad*8];
    }
    float* xb = x1 + (size_t)b*NN*CC + (size_t)h*DD + dt0*16 + mrow;
    // Stage B: 13 n-tiles over 4 waves; each fw fragment used by both d-tiles
    #pragma unroll
    for (int i = 0; i < 4; i++) {
        int n0t = wv + i*4;
        if (n0t < 13) {
            floatx4 a0 = (floatx4){0.f,0.f,0.f,0.f};
            floatx4 a1 = (floatx4){0.f,0.f,0.f,0.f};
            #pragma unroll
            for (int kc = 0; kc < 7; kc++) {
                short8 f0 = *(const short8*)&fw[(size_t)(n0t*16 + mrow)*NP + kc*32 + quad*8];
                a0 = __builtin_amdgcn_mfma_f32_16x16x32_bf16(f0, yf0[kc], a0, 0, 0, 0);
                a1 = __builtin_amdgcn_mfma_f32_16x16x32_bf16(f0, yf1[kc], a1, 0, 0, 0);
            }
            #pragma unroll
            for (int r = 0; r < 4; r++) {
                int n = n0t*16 + quad*4 + r;
                if (n < NN) {
                    xb[(size_t)n*CC]      += a0[r] + bias[n];
                    xb[(size_t)n*CC + 16] += a1[r] + bias[n];
                }
            }
        }
    }
}

// ---------------------------------------------------------------------------
extern "C" void kernel_launch(void* const* d_in, const int* in_sizes, int n_in,
                              void* d_out, int out_size, void* d_ws, size_t ws_size,
                              hipStream_t stream) {
    const float* x     = (const float*)d_in[0];
    const float* qkv_w = (const float*)d_in[1];
    const float* fc_w  = (const float*)d_in[2];
    const float* fc_b  = (const float*)d_in[3];
    const float* alng  = (const float*)d_in[4];
    const float* alnb  = (const float*)d_in[5];
    const float* fc2w  = (const float*)d_in[6];
    const float* fc2b  = (const float*)d_in[7];
    const float* w1    = (const float*)d_in[8];
    const float* b1    = (const float*)d_in[9];
    const float* w2    = (const float*)d_in[10];
    const float* b2    = (const float*)d_in[11];
    const float* flng  = (const float*)d_in[12];
    const float* flnb  = (const float*)d_in[13];
    const float* glng  = (const float*)d_in[14];
    const float* glnb  = (const float*)d_in[15];
    float* out = (float*)d_out;

    float* ws = (float*)d_ws;
    size_t off = 0;
    float* x1 = ws + off; off += (size_t)RR*CC;
    float* x2 = ws + off; off += (size_t)RR*CC;
    float* part = ws + off; off += (size_t)2*RR*CC;     // MLP2 split-K partials
    unsigned short* lnb = (unsigned short*)(ws + off); off += (size_t)RR*CC/2;
    // qkv bf16 region: q[bh][n][64], k[bh][n][64], vT[bh][64][NP]
    unsigned short* qkvo = (unsigned short*)(ws + off);
    unsigned short* qb = qkvo;
    unsigned short* kb = qkvo + (size_t)BHH*NN*DD;
    unsigned short* vT = qkvo + (size_t)2*BHH*NN*DD;
    off += ((size_t)2*BHH*NN*DD + (size_t)BHH*DD*NP + 1) / 2;
    unsigned short* PT   = (unsigned short*)(ws + off); off += (size_t)BHH*NP*NP/2;
    unsigned short* hid  = (unsigned short*)(ws + off); off += (size_t)RR*HIDD/2;
    unsigned short* qkv_wt = (unsigned short*)(ws + off); off += (size_t)3*CC*CC/2;
    unsigned short* w1t    = (unsigned short*)(ws + off); off += (size_t)CC*HIDD/2;
    unsigned short* w2t    = (unsigned short*)(ws + off); off += (size_t)CC*HIDD/2;
    unsigned short* fc_wt  = (unsigned short*)(ws + off); off += (size_t)NP*NP/2 + 16;
    unsigned short* fc2_wt = (unsigned short*)(ws + off); off += (size_t)NP*NP/2 + 16;

    // Zero pads: vT (n-pad cols must be 0), fc_wt/fc2_wt (pad rows/cols).
    hipMemsetAsync(vT, 0, (size_t)BHH*DD*NP*2, stream);
    hipMemsetAsync(fc_wt, 0, (size_t)NP*NP*2, stream);
    hipMemsetAsync(fc2_wt, 0, (size_t)NP*NP*2, stream);

    // Weight prep: bf16 transposed (+padded) copies, once per launch.
    transpose_cast<<<dim3(72, 24), 256, 0, stream>>>(qkv_w, qkv_wt, CC, 3*CC, CC);
    transpose_cast<<<dim3(96, 24), 256, 0, stream>>>(w1, w1t, CC, HIDD, CC);
    transpose_cast<<<dim3(24, 96), 256, 0, stream>>>(w2, w2t, HIDD, CC, HIDD);
    transpose_cast<<<dim3(7, 7),   256, 0, stream>>>(fc_w,  fc_wt,  NN, KWW, NP);
    transpose_cast<<<dim3(7, 7),   256, 0, stream>>>(fc2w,  fc2_wt, KWW, NN, NP);

    // init x1=x2=x fused with layer-0 f-LN -> lnb
    init_ln<<<RR, 192, 0, stream>>>(x, x1, x2, flng, flnb, lnb);

    const int MT = (RR + 127) / 128;   // 50 row-tiles
    for (int l = 0; l < NL; l++) {
        // --- attention branch: y1 = x1 + attn(LN(x2)) ---  (lnb holds f-LN(x2))
        gemm128<4,1><<<dim3(3*CC/128, MT), 256, 0, stream>>>(
            lnb, qkv_wt, nullptr, nullptr, qb, RR, 3*CC, CC);
        // fused qk + fc + LN + softmax -> PT (transposed bf16)
        attn_score<<<dim3(4, BHH), 256, 0, stream>>>(
            qb, kb, fc_wt, fc_b, alng, alnb, PT);
        // fused yv + fc2 -> x1 += (2 d-tiles per block)
        attn_out2<<<dim3(2, BHH), 256, 0, stream>>>(PT, vT, fc2_wt, fc2b, x1);
        // --- mlp branch: y2 = x2 + mlp(LN(y1)) ---
        ln768_kernel<<<RR, 192, 0, stream>>>(x1, glng + l*CC, glnb + l*CC, lnb);
        gemm128<2,1><<<dim3(HIDD/128, MT), 256, 0, stream>>>(
            lnb, w1t, b1, nullptr, hid, RR, HIDD, CC);
        // MLP2: split-K=2, 6 x 50 x 2 = 600 blocks
        gemm128<5,2><<<dim3(CC/128, MT, 2), 256, 0, stream>>>(
            hid, w2t, nullptr, part, nullptr, RR, CC, HIDD);
        // x2 += part0+part1+b2; mode 1 = fuse next layer f-LN; mode 2 (last) =
        // final output 0.5*(x1+x2new) written directly to out.
        if (l + 1 < NL) {
            reduce_ln<<<RR, 192, 0, stream>>>(
                x2, part, b2, flng + (l+1)*CC, flnb + (l+1)*CC, lnb,
                nullptr, nullptr, 1);
        } else {
            reduce_ln<<<RR, 192, 0, stream>>>(
                x2, part, b2, nullptr, nullptr, nullptr, x1, out, 2);
        }
    }
}